// Round 1
// baseline (7490.775 us; speedup 1.0000x reference)
//
#include <hip/hip_runtime.h>
#include <math.h>

namespace {

constexpr int N_   = 200;   // nodes
constexpr int H_   = 20;    // inner steps
constexpr int B_   = 400;   // outer steps
constexpr int OUT_ = 64;    // eeg channels
constexpr int BUF_ = 500;   // hE buffer length
constexpr int NT_  = 1024;  // 16 waves, single persistent workgroup
constexpr int HD_  = 50;    // history depth (max delay 49)
constexpr int HS_  = 51;    // transposed history stride (histT[j*HS_+c])
constexpr int GT0  = 224;   // first gather thread
constexpr int NG_  = 800;   // gather threads (4 per row)
constexpr int EPT  = 50;    // entries per gather thread
constexpr int CAP  = 16;    // CSR capacity (d==0 / d==1)
constexpr int UNR  = 12;    // unrolled CSR entries

constexpr float L2E = 1.4426950408889634f;
constexpr float LN2 = 0.6931471805599453f;

constexpr float DT_  = 0.0001f;
constexpr float G_   = 1000.01f;
constexpr float C1_  = 135.01f;
constexpr float C2_  = 108.01f;
constexpr float C3_  = 33.76f;
constexpr float C4_  = 33.76f;
constexpr float STD_ = 250.0f;
constexpr float K_   = 5.5f;
constexpr float CY0_ = 5.0f;
constexpr float Y0_  = 2.0f;

constexpr float RL2E = 0.56f * L2E;
constexpr float V0R  = 6.0f * RL2E;
constexpr float TU_  = 2.0f * L2E / 500.0f;
constexpr float TS_  = 2.0f * L2E / 1000.0f;

// ddXv = Xv + DT*(A*a*u - 2a*Xv - a^2*X)
constexpr float KMv = 0.9798f, KMu = 0.0328250f, KMx = 1.0201f;
constexpr float KEv = 0.9798f, KEu = 0.0328250f, KEx = 1.0201f;
constexpr float KIv = 0.9898f, KIu = 0.1122000f, KIx = 0.2601f;

__device__ __forceinline__ float fexp2(float x){ return __builtin_amdgcn_exp2f(x); }
__device__ __forceinline__ float flog2(float x){ return __builtin_amdgcn_logf(x); }
__device__ __forceinline__ float frcp (float x){ return __builtin_amdgcn_rcpf(x); }

__device__ __forceinline__ float sigf(float x){
    return 5.0f * frcp(1.0f + fexp2(fmaf(-RL2E, x, V0R)));
}
__device__ __forceinline__ float tanh500(float x){
    return 500.0f - 1000.0f * frcp(1.0f + fexp2(x * TU_));
}
__device__ __forceinline__ float satf(float x){
    return 1000.0f - 2000.0f * frcp(1.0f + fexp2(x * TS_));
}
__device__ __forceinline__ float wl_f(const float* __restrict__ wbb,
                                      const float* __restrict__ sc,
                                      int i, int j){
    float w0 = fexp2(wbb[i*N_+j]*L2E) * sc[i*N_+j];
    float w1 = fexp2(wbb[j*N_+i]*L2E) * sc[j*N_+i];
    return flog2(1.0f + 0.5f*(w0+w1)) * LN2;
}

// 4-step-period pipeline: the only cross-row dependence is LEd(t) <- M(j,t),
// and M(j,t) feeds E(i,t+2) at the earliest.  Given neighbors' M through T,
// each row locally advances rE->T, Ev->T+1, E->T+2, uM->T+2, Mv->T+3, M->T+4.
// So the M/Mv chain runs 4 steps AHEAD of the E chain and rows exchange M in
// float4 blocks: ONE barrier + ONE ds_read_b128 per d0-entry per 4 steps
// (was 4 barriers + 4 scattered b32 reads).  Period blocks align with outer
// steps (5 periods x 4 = 20), so boundary work (histT col, d==1 ledst, eeg)
// sees M_end(s) as element .x of the freshly published block.
__global__ void __launch_bounds__(NT_)
jansen_kernel(
    const float* __restrict__ input,     // (N,H,B)
    const float* __restrict__ noise_in,  // (N,H,B,3)
    const float* __restrict__ hx,        // (N,6)
    const float* __restrict__ hEin,      // (N,500)
    const float* __restrict__ wbb,       // (N,N)
    const float* __restrict__ lm,        // (64,N)
    const float* __restrict__ sc,        // (N,N)
    const int*   __restrict__ dist,      // (N,N)
    float* __restrict__ out,             // 64*400 eeg + N*6 state
    float2* __restrict__ tab)            // d_ws: 40000 x (w, meta)
{
    __shared__ float histT[N_*HS_];          // transposed circular M history
    __shared__ float4 uslab4[N_*(H_/4)];     // u slab, [N][20] as [N][5]xfloat4
    __shared__ float4 neslab4[N_*(H_/4)];    // noise slab, same layout
    __shared__ float d0w_l[CAP*N_];          // d==0 CSR weights (SoA)
    __shared__ unsigned char d0j_l[CAP*N_];  // d==0 CSR j (u8)
    __shared__ float d1w_l[CAP*N_];          // d==1 CSR weights
    __shared__ unsigned char d1j_l[CAP*N_];  // d==1 CSR j
    __shared__ float led_part[4*N_];         // static-gather partials
    __shared__ float4 mcol4[2*N_];           // double-buffered M(t0..t0+3) blocks
    __shared__ float emi[N_];
    __shared__ float colmean[N_];
    __shared__ float lmrs[OUT_];
    __shared__ float red_s[NT_/64];
    __shared__ float norm_s;

    float* uslabF  = (float*)uslab4;         // scalar alias, index ii*H_+hh
    float* neslabF = (float*)neslab4;

    const int t = threadIdx.x;
    const bool isr = (t < N_);
    const bool isg = (t >= GT0);             // 800 gather threads
    const int  gt  = t - GT0;                // 0..799
    const int  grow  = gt >> 2;              // row 0..199
    const int  gslot = gt & 3;               // slot 0..3
    const int  jbase = gslot * EPT;          // this thread's first j
    const int  tb    = gt * EPT;             // table base index

    int sidx[5];                             // slab LDS float indices (gather)
    int goff[5];                             // slab global offsets sans sn

    // ===== S0: lmrs + state/hist init + initial slab (b=0) =====
    if (t < OUT_){
        float s2 = 0.f;
        for (int j=0;j<N_;++j) s2 += fabsf(lm[t*N_+j]);
        lmrs[t] = s2;
    }
    float M=0,E=0,I=0,Mv=0,Ev=0,Iv=0, rowsum=0, ledst=0;
    int cnt0=0, cnt1=0;
    #pragma unroll
    for (int r=0;r<5;++r){ sidx[r]=0; goff[r]=0; }
    if (isg){
        #pragma unroll
        for (int r=0;r<5;++r){
            int p = r*NG_ + gt;
            int hh = p / N_, ii = p - hh*N_;
            sidx[r] = ii*H_ + hh;            // [N][20] layout
            goff[r] = ii*(H_*B_) + hh*B_;
            uslabF[sidx[r]]  = input[goff[r]];
            neslabF[sidx[r]] = noise_in[goff[r]*3];
        }
    }
    if (isr){
        // initial hEb col k (k=1..49) -> slot (0-k) mod 50 = 50-k
        for (int k=1;k<HD_;++k) histT[t*HS_ + (HD_-k)] = hEin[t*BUF_+k];
        M=hx[t*6+0]; E=hx[t*6+1]; I=hx[t*6+2];
        Mv=hx[t*6+3]; Ev=hx[t*6+4]; Iv=hx[t*6+5];
    }
    __syncthreads();

    // ===== S1: compute wl entries -> RAW table; Frobenius + rowsum =====
    float ss = 0.f, rs = 0.f;
    for (int m=0;m<EPT;++m){
        float w = 0.f; int d = 2;
        int j = jbase + m;
        if (isg){
            d = dist[j*N_+grow] >> 1;        // delays[j][grow]
            w = wl_f(wbb, sc, grow, j);
        }
        ss = fmaf(w,w,ss); rs += w;
        if (isg){
            int dm = (d<2) ? 2 : d;          // d<2 handled by CSRs
            float ws = (d>=2) ? w : 0.f;
            tab[tb+m] = make_float2(ws, __uint_as_float((unsigned)j | ((unsigned)dm<<16)));
        }
    }
    if (isr){                                 // colmean (needs lmrs)
        float cm=0.f;
        for (int o=0;o<OUT_;++o) cm += lm[o*N_+t] * frcp(lmrs[o]);
        colmean[t] = cm * (1.0f/(float)OUT_);
    }
    #pragma unroll
    for (int o=32;o>0;o>>=1) ss += __shfl_down(ss,o,64);
    if ((t&63)==0) red_s[t>>6] = ss;
    __syncthreads();
    if (t==0){ float tot=0.f; for (int w=0;w<NT_/64;++w) tot+=red_s[w]; norm_s = sqrtf(tot); }
    __syncthreads();
    const float inv = 1.0f / norm_s;
    // fixup: normalize table weights in place
    if (isg){
        float* tf = (float*)tab;
        for (int m=0;m<EPT;++m) tf[2*(tb+m)] *= inv;
    }
    if (isg) led_part[gslot*N_+grow] = rs;    // raw rowsum partial

    // ===== S3: row CSR build (d<2), registers for d0 =====
    float dw[UNR]; unsigned jpk[3];
    #pragma unroll
    for (int k=0;k<UNR;++k) dw[k] = 0.f;
    jpk[0]=jpk[1]=jpk[2]=0u;
    if (isr){
        #pragma unroll
        for (int k=0;k<UNR;++k){ d0w_l[k*N_+t]=0.f; d0j_l[k*N_+t]=0;
                                 d1w_l[k*N_+t]=0.f; d1j_l[k*N_+t]=0; }
        for (int j=0;j<N_;++j){
            int dd = dist[j*N_+t] >> 1;
            if (dd < 2){
                float w = wl_f(wbb, sc, t, j) * inv;
                if (dd==0){ if (cnt0<CAP){ d0w_l[cnt0*N_+t]=w; d0j_l[cnt0*N_+t]=(unsigned char)j; ++cnt0; } }
                else      { if (cnt1<CAP){ d1w_l[cnt1*N_+t]=w; d1j_l[cnt1*N_+t]=(unsigned char)j; ++cnt1; } }
            }
        }
        #pragma unroll
        for (int k=0;k<UNR;++k){
            dw[k] = d0w_l[k*N_+t];
            unsigned jv = d0j_l[k*N_+t];
            jpk[k>>2] |= jv << ((k&3)*8);
        }
    }
    __syncthreads();

    // ===== S4: rowsum =====
    if (isr){
        rowsum = (led_part[t]+led_part[N_+t]+led_part[2*N_+t]+led_part[3*N_+t]) * inv;
    }
    __syncthreads();

    // ===== S5: initial static gather for s=0 (target step 0 -> c = 50-d) =====
    if (isg){
        float a0 = 0.f;
        for (int m=0;m<EPT;++m){
            float2 e = tab[tb+m];
            unsigned um = __float_as_uint(e.y);
            int c = HD_ - (int)(um>>16);     // d in [2,49] -> c in [1,48]
            a0 = fmaf(e.x, histT[(um&0xFFFFu)*HS_ + c], a0);
        }
        led_part[gslot*N_+grow] = a0;
    }
    __syncthreads();

    // ===== S6: initial ledst (+ d==1 from hE col 1 = slot 49) =====
    if (isr){
        float v = led_part[t]+led_part[N_+t]+led_part[2*N_+t]+led_part[3*N_+t];
        #pragma unroll
        for (int k=0;k<UNR;++k)
            v = fmaf(d1w_l[k*N_+t], histT[(int)d1j_l[k*N_+t]*HS_ + 49], v);
        for (int k=UNR;k<cnt1;++k)
            v = fmaf(d1w_l[k*N_+t], histT[(int)d1j_l[k*N_+t]*HS_ + 49], v);
        ledst = v;
    }

    // ===== prologue: establish 4-step pipeline registers =====
    // Carries entering a period with rE-block t0:
    //   E0=E(t0) E1=E(t0+1) Ev0=Ev(t0) I0=I(t0) I1=I(t0+1) Iv0=Iv(t0)
    //   Mv2=Mv(t0+2) M0..M3=M(t0..t0+3)
    float E0=E, E1=0, Ev0=Ev, I0=I, I1=0, Iv0=Iv;
    float Mv2=0, M0=M, M1=0, M2=0, M3=0, MvOut=Mv;
    if (isr){
        E1 = satf(fmaf(DT_, Ev0, E0));
        I1 = satf(fmaf(DT_, Iv0, I0));
        float uM0 = tanh500(sigf(E0 - I0));
        float Mv1 = satf(fmaf(KMv, Mv, fmaf(KMu, uM0, -KMx*M0)));
        M1 = satf(fmaf(DT_, Mv, M0));
        float uM1 = tanh500(sigf(E1 - I1));
        Mv2 = satf(fmaf(KMv, Mv1, fmaf(KMu, uM1, -KMx*M1)));
        M2 = satf(fmaf(DT_, Mv1, M1));
        M3 = satf(fmaf(DT_, Mv2, M2));
        // block 0 read by period 0: element .x must be hE col0 (reference
        // quirk: the very first inner step reads hE[:,0], not M(0)).
        mcol4[t] = make_float4(hEin[t*BUF_], M1, M2, M3);
    }
    __syncthreads();

    // ===== main loop: 400 outer x (5 periods x 4 pipelined inner steps) =====
    int smod = 0;
    int P = 0;                                  // global period index (parity)
    for (int s=0; s<B_; ++s){
        int ts = smod+1; if (ts==HD_) ts = 0;   // (s+1) % 50
        float acc = 0.f;
        #pragma unroll 1
        for (int q=0; q<5; ++q){
            if (isg){
                // 10 static-gather entries per period, as 5 dwordx4 loads
                const float4* t4 = (const float4*)(tab + tb + q*10);
                #pragma unroll
                for (int m=0;m<5;++m){
                    float4 ee = t4[m];
                    unsigned um0 = __float_as_uint(ee.y);
                    int c0 = ts - (int)(um0>>16); if (c0<0) c0 += HD_;
                    acc = fmaf(ee.x, histT[(um0&0xFFFFu)*HS_ + c0], acc);
                    unsigned um1 = __float_as_uint(ee.w);
                    int c1 = ts - (int)(um1>>16); if (c1<0) c1 += HD_;
                    acc = fmaf(ee.z, histT[(um1&0xFFFFu)*HS_ + c1], acc);
                }
            }
            if (isr){
                const float4* rb = mcol4 + (P&1)*N_;        // neighbors' M(t0..t0+3)
                float4*       wb = mcol4 + ((P+1)&1)*N_;
                // d0 gather: 16 partials preserve the old per-step rounding
                // (step k: pk0=ledst+e0+e4+e8, pk1=e1+e5+e9, ...)
                float p00=ledst, p01=0.f, p02=0.f, p03=0.f;
                float p10=ledst, p11=0.f, p12=0.f, p13=0.f;
                float p20=ledst, p21=0.f, p22=0.f, p23=0.f;
                float p30=ledst, p31=0.f, p32=0.f, p33=0.f;
                #pragma unroll
                for (int k=0;k<UNR;++k){
                    int j = (jpk[k>>2] >> ((k&3)*8)) & 255;
                    float4 mj = rb[j];
                    float w = dw[k];
                    if ((k&3)==0){ p00=fmaf(w,mj.x,p00); p10=fmaf(w,mj.y,p10);
                                   p20=fmaf(w,mj.z,p20); p30=fmaf(w,mj.w,p30); }
                    else if ((k&3)==1){ p01=fmaf(w,mj.x,p01); p11=fmaf(w,mj.y,p11);
                                        p21=fmaf(w,mj.z,p21); p31=fmaf(w,mj.w,p31); }
                    else if ((k&3)==2){ p02=fmaf(w,mj.x,p02); p12=fmaf(w,mj.y,p12);
                                        p22=fmaf(w,mj.z,p22); p32=fmaf(w,mj.w,p32); }
                    else              { p03=fmaf(w,mj.x,p03); p13=fmaf(w,mj.y,p13);
                                        p23=fmaf(w,mj.z,p23); p33=fmaf(w,mj.w,p33); }
                }
                for (int k=UNR;k<cnt0;++k){
                    float w = d0w_l[k*N_+t];
                    float4 mj = rb[d0j_l[k*N_+t]];
                    p00=fmaf(w,mj.x,p00); p10=fmaf(w,mj.y,p10);
                    p20=fmaf(w,mj.z,p20); p30=fmaf(w,mj.w,p30);
                }
                float la0 = (p00+p01)+(p02+p03);
                float la1 = (p10+p11)+(p12+p13);
                float la2 = (p20+p21)+(p22+p23);
                float la3 = (p30+p31)+(p32+p33);
                const float4 uu = uslab4[t*(H_/4)+q];
                const float4 nn = neslab4[t*(H_/4)+q];
                // ---- step t0+0 ----
                float rE0 = fmaf(STD_, nn.x, G_*(la0 - rowsum*E0)) + C2_*sigf(C1_*M0);
                float uE0 = fmaf(K_, uu.x, tanh500(rE0));
                float Ev1 = satf(fmaf(KEv, Ev0, fmaf(KEu, uE0, -KEx*E0)));
                float E2  = satf(fmaf(DT_, Ev1, E1));
                float uI0 = tanh500(C4_*sigf(C3_*M0));
                float Iv1 = satf(fmaf(KIv, Iv0, fmaf(KIu, uI0, -KIx*I0)));
                float I2  = satf(fmaf(DT_, Iv1, I1));
                float uM2 = tanh500(sigf(E2 - I2));
                float Mv3 = satf(fmaf(KMv, Mv2, fmaf(KMu, uM2, -KMx*M2)));
                float M4  = satf(fmaf(DT_, Mv3, M3));
                // ---- step t0+1 ----
                float rE1 = fmaf(STD_, nn.y, G_*(la1 - rowsum*E1)) + C2_*sigf(C1_*M1);
                float uE1 = fmaf(K_, uu.y, tanh500(rE1));
                float Ev2 = satf(fmaf(KEv, Ev1, fmaf(KEu, uE1, -KEx*E1)));
                float E3  = satf(fmaf(DT_, Ev2, E2));
                float uI1 = tanh500(C4_*sigf(C3_*M1));
                float Iv2 = satf(fmaf(KIv, Iv1, fmaf(KIu, uI1, -KIx*I1)));
                float I3  = satf(fmaf(DT_, Iv2, I2));
                float uM3 = tanh500(sigf(E3 - I3));
                float Mv4 = satf(fmaf(KMv, Mv3, fmaf(KMu, uM3, -KMx*M3)));
                float M5  = satf(fmaf(DT_, Mv4, M4));
                // ---- step t0+2 ----
                float rE2 = fmaf(STD_, nn.z, G_*(la2 - rowsum*E2)) + C2_*sigf(C1_*M2);
                float uE2 = fmaf(K_, uu.z, tanh500(rE2));
                float Ev3 = satf(fmaf(KEv, Ev2, fmaf(KEu, uE2, -KEx*E2)));
                float E4  = satf(fmaf(DT_, Ev3, E3));
                float uI2 = tanh500(C4_*sigf(C3_*M2));
                float Iv3 = satf(fmaf(KIv, Iv2, fmaf(KIu, uI2, -KIx*I2)));
                float I4  = satf(fmaf(DT_, Iv3, I3));
                float uM4 = tanh500(sigf(E4 - I4));
                float Mv5 = satf(fmaf(KMv, Mv4, fmaf(KMu, uM4, -KMx*M4)));
                float M6  = satf(fmaf(DT_, Mv5, M5));
                // ---- step t0+3 ----
                float rE3 = fmaf(STD_, nn.w, G_*(la3 - rowsum*E3)) + C2_*sigf(C1_*M3);
                float uE3 = fmaf(K_, uu.w, tanh500(rE3));
                float Ev4 = satf(fmaf(KEv, Ev3, fmaf(KEu, uE3, -KEx*E3)));
                float E5  = satf(fmaf(DT_, Ev4, E4));
                float uI3 = tanh500(C4_*sigf(C3_*M3));
                float Iv4 = satf(fmaf(KIv, Iv3, fmaf(KIu, uI3, -KIx*I3)));
                float I5  = satf(fmaf(DT_, Iv4, I4));
                float uM5 = tanh500(sigf(E5 - I5));
                float Mv6 = satf(fmaf(KMv, Mv5, fmaf(KMu, uM5, -KMx*M5)));
                float M7  = satf(fmaf(DT_, Mv6, M6));
                // publish next block + rotate carries
                wb[t] = make_float4(M4, M5, M6, M7);
                MvOut = Mv4;                   // Mv at an outer/final boundary
                E0=E4; E1=E5; Ev0=Ev4;
                I0=I4; I1=I5; Iv0=Iv4;
                Mv2=Mv6; M0=M4; M1=M5; M2=M6; M3=M7;
            }
            ++P;
            __syncthreads();
        }
        // ===== outer boundary =====
        // After the 5th period: E0=E(20(s+1)), I0=I(20(s+1)), M0=M(20(s+1)),
        // and the just-published block (buffer P&1) has M_end(s) in .x.
        if (isr){ histT[t*HS_ + smod] = M0; emi[t] = E0 - I0; }
        if (isg){
            led_part[gslot*N_+grow] = acc;
            // stage u/ne slab for s+1 (one L2/HBM drain per outer step)
            int sn = s+1; if (sn >= B_) sn = B_-1;
            #pragma unroll
            for (int r=0;r<5;++r){
                uslabF[sidx[r]]  = input[goff[r] + sn];
                neslabF[sidx[r]] = noise_in[(goff[r] + sn)*3];
            }
        }
        __syncthreads();
        if (isr){
            const float4* rb2 = mcol4 + (P&1)*N_;
            float v = led_part[t]+led_part[N_+t]+led_part[2*N_+t]+led_part[3*N_+t];
            // d==1 term for outer s+1: M_end(s) = .x of the published block
            #pragma unroll
            for (int k=0;k<UNR;++k)
                v = fmaf(d1w_l[k*N_+t], rb2[d1j_l[k*N_+t]].x, v);
            for (int k=UNR;k<cnt1;++k)
                v = fmaf(d1w_l[k*N_+t], rb2[d1j_l[k*N_+t]].x, v);
            ledst = v;
        }
        {   // eeg
            int o = t>>4, l = t&15;
            float il = frcp(lmrs[o]);
            float a2 = 0.f;
            for (int j=l;j<N_;j+=16)
                a2 = fmaf(fmaf(lm[o*N_+j], il, -colmean[j]), emi[j], a2);
            a2 += __shfl_down(a2,8,16); a2 += __shfl_down(a2,4,16);
            a2 += __shfl_down(a2,2,16); a2 += __shfl_down(a2,1,16);
            if (l==0) out[o*B_+s] = fmaf(CY0_, a2, -Y0_);
        }
        smod = ts;
        __syncthreads();
    }

    // final state: E-pace carries are exactly state(8000); Mv via MvOut
    if (isr){
        float* cs = out + OUT_*B_ + t*6;
        cs[0]=M0; cs[1]=E0; cs[2]=I0; cs[3]=MvOut; cs[4]=Ev0; cs[5]=Iv0;
    }
}

} // namespace

extern "C" void kernel_launch(void* const* d_in, const int* in_sizes, int n_in,
                              void* d_out, int out_size, void* d_ws, size_t ws_size,
                              hipStream_t stream)
{
    const float* input    = (const float*)d_in[0];
    const float* noise_in = (const float*)d_in[1];
    const float* hx   = (const float*)d_in[3];
    const float* hEin = (const float*)d_in[4];
    const float* wbb  = (const float*)d_in[5];
    const float* lm   = (const float*)d_in[6];
    const float* sc   = (const float*)d_in[7];
    const int*   dist = (const int*)d_in[8];
    float* out = (float*)d_out;
    float2* tab = (float2*)((char*)d_ws + 1024);   // 40000 x 8B = 320KB

    hipLaunchKernelGGL(jansen_kernel, dim3(1), dim3(NT_), 0, stream,
                       input, noise_in, hx, hEin, wbb, lm, sc, dist, out, tab);
}

// Round 2
// 5937.006 us; speedup vs baseline: 1.2617x; 1.2617x over previous
//
#include <hip/hip_runtime.h>
#include <math.h>

namespace {

constexpr int N_   = 200;   // nodes
constexpr int H_   = 20;    // inner steps
constexpr int B_   = 400;   // outer steps
constexpr int OUT_ = 64;    // eeg channels
constexpr int BUF_ = 500;   // hE buffer length
constexpr int NT_  = 1024;  // 16 waves, single persistent workgroup
constexpr int HD_  = 50;    // history depth (max delay 49)
constexpr int HS_  = 51;    // transposed history stride (histT[j*HS_+c])
constexpr int GT0  = 224;   // first gather thread (INIT phases only)
constexpr int NG_  = 800;   // gather units (4 per row)
constexpr int EPT  = 50;    // entries per gather unit
constexpr int CAP  = 16;    // CSR capacity (d==0 / d==1)
constexpr int UNR  = 12;    // unrolled CSR entries
constexpr int RW_  = 256;   // row-group threads (waves 0-3, lockstep)
constexpr int NFREE = NT_ - RW_;   // 768 free-running gather threads
constexpr int SLAB  = H_ * N_;     // 4000 slab elements

constexpr float L2E = 1.4426950408889634f;
constexpr float LN2 = 0.6931471805599453f;

constexpr float DT_  = 0.0001f;
constexpr float G_   = 1000.01f;
constexpr float C1_  = 135.01f;
constexpr float C2_  = 108.01f;
constexpr float C3_  = 33.76f;
constexpr float C4_  = 33.76f;
constexpr float STD_ = 250.0f;
constexpr float K_   = 5.5f;
constexpr float CY0_ = 5.0f;
constexpr float Y0_  = 2.0f;

constexpr float RL2E = 0.56f * L2E;
constexpr float V0R  = 6.0f * RL2E;
constexpr float TU_  = 2.0f * L2E / 500.0f;
constexpr float TS_  = 2.0f * L2E / 1000.0f;

// ddXv = Xv + DT*(A*a*u - 2a*Xv - a^2*X)
constexpr float KMv = 0.9798f, KMu = 0.0328250f, KMx = 1.0201f;
constexpr float KEv = 0.9798f, KEu = 0.0328250f, KEx = 1.0201f;
constexpr float KIv = 0.9898f, KIu = 0.1122000f, KIx = 0.2601f;

__device__ __forceinline__ float fexp2(float x){ return __builtin_amdgcn_exp2f(x); }
__device__ __forceinline__ float flog2(float x){ return __builtin_amdgcn_logf(x); }
__device__ __forceinline__ float frcp (float x){ return __builtin_amdgcn_rcpf(x); }

__device__ __forceinline__ float sigf(float x){
    return 5.0f * frcp(1.0f + fexp2(fmaf(-RL2E, x, V0R)));
}
__device__ __forceinline__ float tanh500(float x){
    return 500.0f - 1000.0f * frcp(1.0f + fexp2(x * TU_));
}
__device__ __forceinline__ float satf(float x){
    return 1000.0f - 2000.0f * frcp(1.0f + fexp2(x * TS_));
}
__device__ __forceinline__ float wl_f(const float* __restrict__ wbb,
                                      const float* __restrict__ sc,
                                      int i, int j){
    float w0 = fexp2(wbb[i*N_+j]*L2E) * sc[i*N_+j];
    float w1 = fexp2(wbb[j*N_+i]*L2E) * sc[j*N_+i];
    return flog2(1.0f + 0.5f*(w0+w1)) * LN2;
}

// Wave-role split: waves 0-3 (rows) lockstep per inner step via a 4-wave LDS
// barrier; waves 4-15 (gather) free-run and only hit the two boundary
// __syncthreads per outer step.  Rationale: within outer step s the static
// gather reads only histT columns frozen since boundary s-1 (it never reads
// columns s%50 / (s+1)%50 -- the only ones rows write), and led_part is
// consumed only at the boundary.  This removes 12 waves' s_barrier arrival
// AND their vmcnt(0) prefetch drains from every one of the 8000 step syncs.
// Custom-barrier safety: increment follows s_waitcnt lgkmcnt(0), which
// drains this wave's mcol reads AND write, so a wave observing cnt>=4k knows
// every wave's step-(k-1) buffer reads have landed in registers before it
// overwrites that buffer.  Rounding is bit-identical to the 6598us kernel:
// gather units (row,slot) are independent 50-entry fma chains, so remapping
// 800 units onto 768 free threads (gf<32 take two) changes no summation
// order; init phases keep the original 224+gt mapping verbatim.
__global__ void __launch_bounds__(NT_)
jansen_kernel(
    const float* __restrict__ input,     // (N,H,B)
    const float* __restrict__ noise_in,  // (N,H,B,3)
    const float* __restrict__ hx,        // (N,6)
    const float* __restrict__ hEin,      // (N,500)
    const float* __restrict__ wbb,       // (N,N)
    const float* __restrict__ lm,        // (64,N)
    const float* __restrict__ sc,        // (N,N)
    const int*   __restrict__ dist,      // (N,N)
    float* __restrict__ out,             // 64*400 eeg + N*6 state
    float2* __restrict__ tab)            // d_ws: 40000 x (w, meta)
{
    __shared__ float histT[N_*HS_];          // transposed circular M history
    __shared__ float uslab[H_*N_];           // u for current outer step
    __shared__ float neslab[H_*N_];          // noise for current outer step
    __shared__ float d0w_l[CAP*N_];          // d==0 CSR weights (SoA)
    __shared__ unsigned char d0j_l[CAP*N_];  // d==0 CSR j (u8)
    __shared__ float d1w_l[CAP*N_];          // d==1 CSR weights
    __shared__ unsigned char d1j_l[CAP*N_];  // d==1 CSR j
    __shared__ float led_part[4*N_];         // static-gather partials
    __shared__ float mcol[2*N_];             // double-buffered hEb col 0
    __shared__ float emi[N_];
    __shared__ float colmean[N_];
    __shared__ float lmrs[OUT_];
    __shared__ float red_s[NT_/64];
    __shared__ float norm_s;
    __shared__ int   rbar;                   // row-wave barrier counter

    const int t = threadIdx.x;
    const bool isr = (t < N_);
    const bool isg = (t >= GT0);             // init-phase gather role
    const int  gt  = t - GT0;                // init-phase unit id 0..799
    const int  grow  = gt >> 2;
    const int  gslot = gt & 3;
    const int  jbase = gslot * EPT;
    const int  tb    = gt * EPT;

    int sidx[5];                             // init slab LDS indices
    int goff[5];                             // init slab global offsets

    // ===== S0: lmrs + state/hist/mcol init + initial slab (b=0) =====
    if (t == 0) rbar = 0;
    if (t < OUT_){
        float s2 = 0.f;
        for (int j=0;j<N_;++j) s2 += fabsf(lm[t*N_+j]);
        lmrs[t] = s2;
    }
    float M=0,E=0,I=0,Mv=0,Ev=0,Iv=0, rowsum=0, ledst=0;
    int cnt0=0, cnt1=0;
    #pragma unroll
    for (int r=0;r<5;++r){ sidx[r]=0; goff[r]=0; }
    if (isg){
        #pragma unroll
        for (int r=0;r<5;++r){
            int p = r*NG_ + gt;
            int hh = p / N_, ii = p - hh*N_;
            sidx[r] = hh*N_ + ii;
            goff[r] = ii*(H_*B_) + hh*B_;
            uslab[sidx[r]]  = input[goff[r]];
            neslab[sidx[r]] = noise_in[goff[r]*3];
        }
    }
    if (isr){
        // initial hEb col k (k=1..49) -> slot (0-k) mod 50 = 50-k
        for (int k=1;k<HD_;++k) histT[t*HS_ + (HD_-k)] = hEin[t*BUF_+k];
        mcol[t] = hEin[t*BUF_];
        M=hx[t*6+0]; E=hx[t*6+1]; I=hx[t*6+2];
        Mv=hx[t*6+3]; Ev=hx[t*6+4]; Iv=hx[t*6+5];
    }
    __syncthreads();

    // ===== S1: compute wl entries -> RAW table; Frobenius + rowsum =====
    float ss = 0.f, rs = 0.f;
    for (int m=0;m<EPT;++m){
        float w = 0.f; int d = 2;
        int j = jbase + m;
        if (isg){
            d = dist[j*N_+grow] >> 1;        // delays[j][grow]
            w = wl_f(wbb, sc, grow, j);
        }
        ss = fmaf(w,w,ss); rs += w;
        if (isg){
            int dm = (d<2) ? 2 : d;          // d<2 handled by CSRs
            float ws = (d>=2) ? w : 0.f;
            tab[tb+m] = make_float2(ws, __uint_as_float((unsigned)j | ((unsigned)dm<<16)));
        }
    }
    if (isr){                                 // colmean (needs lmrs)
        float cm=0.f;
        for (int o=0;o<OUT_;++o) cm += lm[o*N_+t] * frcp(lmrs[o]);
        colmean[t] = cm * (1.0f/(float)OUT_);
    }
    #pragma unroll
    for (int o=32;o>0;o>>=1) ss += __shfl_down(ss,o,64);
    if ((t&63)==0) red_s[t>>6] = ss;
    __syncthreads();
    if (t==0){ float tot=0.f; for (int w=0;w<NT_/64;++w) tot+=red_s[w]; norm_s = sqrtf(tot); }
    __syncthreads();
    const float inv = 1.0f / norm_s;
    // fixup: normalize table weights in place
    if (isg){
        float* tf = (float*)tab;
        for (int m=0;m<EPT;++m) tf[2*(tb+m)] *= inv;
    }
    if (isg) led_part[gslot*N_+grow] = rs;    // raw rowsum partial

    // ===== S3: row CSR build (d<2), registers for d0 =====
    float dw[UNR]; unsigned jpk[3];
    #pragma unroll
    for (int k=0;k<UNR;++k) dw[k] = 0.f;
    jpk[0]=jpk[1]=jpk[2]=0u;
    if (isr){
        #pragma unroll
        for (int k=0;k<UNR;++k){ d0w_l[k*N_+t]=0.f; d0j_l[k*N_+t]=0;
                                 d1w_l[k*N_+t]=0.f; d1j_l[k*N_+t]=0; }
        for (int j=0;j<N_;++j){
            int dd = dist[j*N_+t] >> 1;
            if (dd < 2){
                float w = wl_f(wbb, sc, t, j) * inv;
                if (dd==0){ if (cnt0<CAP){ d0w_l[cnt0*N_+t]=w; d0j_l[cnt0*N_+t]=(unsigned char)j; ++cnt0; } }
                else      { if (cnt1<CAP){ d1w_l[cnt1*N_+t]=w; d1j_l[cnt1*N_+t]=(unsigned char)j; ++cnt1; } }
            }
        }
        #pragma unroll
        for (int k=0;k<UNR;++k){
            dw[k] = d0w_l[k*N_+t];
            unsigned jv = d0j_l[k*N_+t];
            jpk[k>>2] |= jv << ((k&3)*8);
        }
    }
    __syncthreads();

    // ===== S4: rowsum =====
    if (isr){
        rowsum = (led_part[t]+led_part[N_+t]+led_part[2*N_+t]+led_part[3*N_+t]) * inv;
    }
    __syncthreads();

    // ===== S5: initial static gather for s=0 (target step 0 -> c = 50-d) =====
    if (isg){
        float a0 = 0.f;
        for (int m=0;m<EPT;++m){
            float2 e = tab[tb+m];
            unsigned um = __float_as_uint(e.y);
            int c = HD_ - (int)(um>>16);     // d in [2,49] -> c in [1,48]
            a0 = fmaf(e.x, histT[(um&0xFFFFu)*HS_ + c], a0);
        }
        led_part[gslot*N_+grow] = a0;
    }
    __syncthreads();

    // ===== S6: initial ledst (+ d==1 from hE col 1 = slot 49) =====
    if (isr){
        float v = led_part[t]+led_part[N_+t]+led_part[2*N_+t]+led_part[3*N_+t];
        #pragma unroll
        for (int k=0;k<UNR;++k)
            v = fmaf(d1w_l[k*N_+t], histT[(int)d1j_l[k*N_+t]*HS_ + 49], v);
        for (int k=UNR;k<cnt1;++k)
            v = fmaf(d1w_l[k*N_+t], histT[(int)d1j_l[k*N_+t]*HS_ + 49], v);
        ledst = v;
    }

    // ===== main-loop free-thread mapping (units + slab staging) =====
    const int gf = t - RW_;                  // 0..767 for free threads
    int sidxM[6], goffM[6];
    bool has6 = false;
    if (t >= RW_){
        #pragma unroll
        for (int r=0;r<6;++r){
            int p = r*NFREE + gf;
            if (p < SLAB){
                int hh = p / N_, ii = p - hh*N_;
                sidxM[r] = hh*N_ + ii;
                goffM[r] = ii*(H_*B_) + hh*B_;
            } else { sidxM[r]=0; goffM[r]=0; }
        }
        has6 = (5*NFREE + gf) < SLAB;        // gf < 160
    }
    __syncthreads();

// one ODE inner step for row threads; MCR/MCW are mcol read/write halves
#define ROW_BODY(MCR, MCW, HH)                                               \
    do {                                                                     \
        float rM  = sigf(E - I);                                             \
        float uM  = tanh500(rM);                                             \
        float Mn  = satf(fmaf(DT_, Mv, M));                                  \
        float Mvn = satf(fmaf(KMv, Mv, fmaf(KMu, uM, -KMx*M)));              \
        (MCW)[t] = Mn;                                                       \
        float rI  = C4_*sigf(C3_*M);                                         \
        float uI  = tanh500(rI);                                             \
        float In  = satf(fmaf(DT_, Iv, I));                                  \
        float Ivn = satf(fmaf(KIv, Iv, fmaf(KIu, uI, -KIx*I)));              \
        float u  = uslab[(HH)*N_+t];                                         \
        float ne = neslab[(HH)*N_+t];                                        \
        float l0 = ledst, l1 = 0.f, l2 = 0.f, l3 = 0.f;                      \
        _Pragma("unroll")                                                    \
        for (int k=0;k<UNR;++k){                                             \
            int j = (jpk[k>>2] >> ((k&3)*8)) & 255;                          \
            float v = (MCR)[j];                                              \
            if      ((k&3)==0) l0 = fmaf(dw[k], v, l0);                      \
            else if ((k&3)==1) l1 = fmaf(dw[k], v, l1);                      \
            else if ((k&3)==2) l2 = fmaf(dw[k], v, l2);                      \
            else               l3 = fmaf(dw[k], v, l3);                      \
        }                                                                    \
        for (int k=UNR;k<cnt0;++k)                                           \
            l0 = fmaf(d0w_l[k*N_+t], (MCR)[d0j_l[k*N_+t]], l0);              \
        float LEd = (l0+l1)+(l2+l3);                                         \
        float rE  = fmaf(STD_, ne, G_*(LEd - rowsum*E)) + C2_*sigf(C1_*M);   \
        float uE  = fmaf(K_, u, tanh500(rE));                                \
        float En  = satf(fmaf(DT_, Ev, E));                                  \
        float Evn = satf(fmaf(KEv, Ev, fmaf(KEu, uE, -KEx*E)));              \
        M=Mn; Mv=Mvn; I=In; Iv=Ivn; E=En; Ev=Evn;                            \
    } while(0)

// 4-wave row barrier: drain own LDS ops, count in, spin to epoch target
#define ROW_SYNC()                                                           \
    do {                                                                     \
        asm volatile("s_waitcnt lgkmcnt(0)" ::: "memory");                   \
        if ((t & 63) == 0) atomicAdd(&rbar, 1);                              \
        ++repoch;                                                            \
        while (*(volatile int*)&rbar < 4*repoch)                             \
            __builtin_amdgcn_s_sleep(1);                                     \
        asm volatile("" ::: "memory");                                       \
    } while(0)

    // ===== main loop: 400 outer x 20 inner =====
    int smod = 0;
    int repoch = 0;
    float su_r[6], sn_r[6];
    for (int s=0; s<B_; ++s){
        int ts = smod+1; if (ts==HD_) ts = 0;      // (s+1) % 50
        if (t < RW_){
            // ---- row waves: 20 lockstep steps, 4-wave sync only ----
            int cur = 0;
            #pragma unroll 2
            for (int h=0; h<H_; ++h){
                if (isr) ROW_BODY(mcol + cur*N_, mcol + (cur^1)*N_, h);
                ROW_SYNC();
                cur ^= 1;
            }
            if (isr){ histT[t*HS_ + smod] = M; emi[t] = E - I; }
        } else {
            // ---- free gather waves: flat 50-entry gather, no step sync ----
            float acc = 0.f;
            {
                const float4* t4 = (const float4*)(tab + (size_t)gf*EPT);
                #pragma unroll 5
                for (int m=0;m<EPT/2;++m){
                    float4 ee = t4[m];
                    unsigned um0 = __float_as_uint(ee.y);
                    int c0 = ts - (int)(um0>>16); if (c0<0) c0 += HD_;
                    acc = fmaf(ee.x, histT[(um0&0xFFFFu)*HS_ + c0], acc);
                    unsigned um1 = __float_as_uint(ee.w);
                    int c1 = ts - (int)(um1>>16); if (c1<0) c1 += HD_;
                    acc = fmaf(ee.z, histT[(um1&0xFFFFu)*HS_ + c1], acc);
                }
            }
            led_part[(gf&3)*N_ + (gf>>2)] = acc;
            if (gf < NG_-NFREE){                    // 32 threads: 2nd unit
                const int u1 = NFREE + gf;
                float acc1 = 0.f;
                const float4* t4 = (const float4*)(tab + (size_t)u1*EPT);
                #pragma unroll 5
                for (int m=0;m<EPT/2;++m){
                    float4 ee = t4[m];
                    unsigned um0 = __float_as_uint(ee.y);
                    int c0 = ts - (int)(um0>>16); if (c0<0) c0 += HD_;
                    acc1 = fmaf(ee.x, histT[(um0&0xFFFFu)*HS_ + c0], acc1);
                    unsigned um1 = __float_as_uint(ee.w);
                    int c1 = ts - (int)(um1>>16); if (c1<0) c1 += HD_;
                    acc1 = fmaf(ee.z, histT[(um1&0xFFFFu)*HS_ + c1], acc1);
                }
                led_part[(u1&3)*N_ + (u1>>2)] = acc1;
            }
            // slab loads for s+1 into registers (LDS write deferred past A)
            int sn = s+1; if (sn >= B_) sn = B_-1;
            #pragma unroll
            for (int r=0;r<5;++r){
                su_r[r] = input[goffM[r] + sn];
                sn_r[r] = noise_in[(goffM[r] + sn)*3];
            }
            if (has6){
                su_r[5] = input[goffM[5] + sn];
                sn_r[5] = noise_in[(goffM[5] + sn)*3];
            }
        }
        __syncthreads();                            // boundary A
        if (isr){
            float v = led_part[t]+led_part[N_+t]+led_part[2*N_+t]+led_part[3*N_+t];
            // d==1 term: col 1 during s+1 is M_end(s) = mcol buffer 0 (H even)
            #pragma unroll
            for (int k=0;k<UNR;++k)
                v = fmaf(d1w_l[k*N_+t], mcol[d1j_l[k*N_+t]], v);
            for (int k=UNR;k<cnt1;++k)
                v = fmaf(d1w_l[k*N_+t], mcol[d1j_l[k*N_+t]], v);
            ledst = v;
        }
        if (t >= RW_){
            // slab LDS writes AFTER A (rows done reading slab for s)
            #pragma unroll
            for (int r=0;r<5;++r){
                uslab[sidxM[r]]  = su_r[r];
                neslab[sidxM[r]] = sn_r[r];
            }
            if (has6){ uslab[sidxM[5]] = su_r[5]; neslab[sidxM[5]] = sn_r[5]; }
        }
        {   // eeg (all threads)
            int o = t>>4, l = t&15;
            float il = frcp(lmrs[o]);
            float a2 = 0.f;
            for (int j=l;j<N_;j+=16)
                a2 = fmaf(fmaf(lm[o*N_+j], il, -colmean[j]), emi[j], a2);
            a2 += __shfl_down(a2,8,16); a2 += __shfl_down(a2,4,16);
            a2 += __shfl_down(a2,2,16); a2 += __shfl_down(a2,1,16);
            if (l==0) out[o*B_+s] = fmaf(CY0_, a2, -Y0_);
        }
        smod = ts;
        __syncthreads();                            // boundary B
    }

#undef ROW_BODY
#undef ROW_SYNC

    // final state
    if (isr){
        float* cs = out + OUT_*B_ + t*6;
        cs[0]=M; cs[1]=E; cs[2]=I; cs[3]=Mv; cs[4]=Ev; cs[5]=Iv;
    }
}

} // namespace

extern "C" void kernel_launch(void* const* d_in, const int* in_sizes, int n_in,
                              void* d_out, int out_size, void* d_ws, size_t ws_size,
                              hipStream_t stream)
{
    const float* input    = (const float*)d_in[0];
    const float* noise_in = (const float*)d_in[1];
    const float* hx   = (const float*)d_in[3];
    const float* hEin = (const float*)d_in[4];
    const float* wbb  = (const float*)d_in[5];
    const float* lm   = (const float*)d_in[6];
    const float* sc   = (const float*)d_in[7];
    const int*   dist = (const int*)d_in[8];
    float* out = (float*)d_out;
    float2* tab = (float2*)((char*)d_ws + 1024);   // 40000 x 8B = 320KB

    hipLaunchKernelGGL(jansen_kernel, dim3(1), dim3(NT_), 0, stream,
                       input, noise_in, hx, hEin, wbb, lm, sc, dist, out, tab);
}